// Round 6
// baseline (658.521 us; speedup 1.0000x reference)
//
#include <hip/hip_runtime.h>
#include <hip/hip_bf16.h>
#include <math.h>
#include <stdint.h>

#define D 128

typedef unsigned short u16;
typedef __attribute__((ext_vector_type(8))) short bf16x8;
typedef __attribute__((ext_vector_type(4))) float f32x4;
typedef __attribute__((ext_vector_type(4))) unsigned short u16x4;

// ws layout: [0,262144) bytes = weight frags (+We1r). Then agg bf16[N*D],
// count int[N], offs int[N], sorted int2[E].
#define FRAG_WE1 0
#define FRAG_WE2 32768
#define FRAG_WC1 49152
#define FRAG_WN1 65536
#define FRAG_WN2 98304
#define WE1R_OFF 114688   // float[128]
#define FRAG_BYTES 262144

__device__ __forceinline__ float silu_f(float x) {
    return x / (1.0f + __expf(-x));
}
__device__ __forceinline__ u16 f2bf(float x) {
    union { float f; unsigned int u; } v; v.f = x;
    unsigned int r = v.u + 0x7fffu + ((v.u >> 16) & 1u);
    return (u16)(r >> 16);
}
__device__ __forceinline__ float bf2f(u16 u) {
    union { unsigned int u; float f; } v; v.u = ((unsigned int)u) << 16; return v.f;
}
__device__ __forceinline__ unsigned pk2bf(float a, float b) {
    union { __hip_bfloat162 v; unsigned u; } u;
    u.v = __float22bfloat162_rn(make_float2(a, b));
    return u.u;
}
__device__ __forceinline__ void pk_agg_add(u16* addr, unsigned packed) {
    asm volatile("global_atomic_pk_add_bf16 %0, %1, off"
                 :: "v"(addr), "v"(packed) : "memory");
}

// ---------------- zero: agg bf16 + count, copy pos -> pos_out ----------------
__global__ __launch_bounds__(256) void egnn_zero(
    const float* __restrict__ pos, float* __restrict__ out,
    uint4* __restrict__ agg4, int* __restrict__ count, int N)
{
    int stride = gridDim.x * blockDim.x;
    int nagg = N * D / 8;
    int total = nagg + N + N * 3;
    for (int i = blockIdx.x * blockDim.x + threadIdx.x; i < total; i += stride) {
        if (i < nagg) agg4[i] = make_uint4(0, 0, 0, 0);
        else if (i < nagg + N) count[i - nagg] = 0;
        else { int j = i - nagg - N; out[(size_t)N * D + j] = pos[j]; }
    }
}

// ---------------- init (fallback): zero fp32 agg (= out h region), copy pos ----------------
__global__ __launch_bounds__(256) void egnn_init_f32(
    const float* __restrict__ pos, float* __restrict__ out, int N)
{
    int stride = gridDim.x * blockDim.x;
    int hd = N * D;
    int total = hd + N * 3;
    for (int i = blockIdx.x * blockDim.x + threadIdx.x; i < total; i += stride)
        out[i] = (i < hd) ? 0.0f : pos[i - hd];
}

// ---------------- counting sort ----------------
__global__ __launch_bounds__(256) void egnn_count(
    const int* __restrict__ eidx, int* __restrict__ count, int E)
{
    int stride = gridDim.x * blockDim.x;
    for (int e = blockIdx.x * blockDim.x + threadIdx.x; e < E; e += stride)
        atomicAdd(&count[eidx[e]], 1);
}

__global__ __launch_bounds__(256) void egnn_scan(
    const int* __restrict__ count, int* __restrict__ offs, int N)
{
    __shared__ int psum[256];
    int t = threadIdx.x;
    int chunk = (N + 255) / 256;
    int s0 = t * chunk, s1 = min(s0 + chunk, N);
    int s = 0;
    for (int i = s0; i < s1; ++i) s += count[i];
    psum[t] = s;
    __syncthreads();
    int acc = 0;
    for (int i = 0; i < t; ++i) acc += psum[i];
    for (int i = s0; i < s1; ++i) { offs[i] = acc; acc += count[i]; }
}

__global__ __launch_bounds__(256) void egnn_scatter(
    const int* __restrict__ eidx, int* __restrict__ offs,
    int2* __restrict__ sorted, int E)
{
    int stride = gridDim.x * blockDim.x;
    for (int e = blockIdx.x * blockDim.x + threadIdx.x; e < E; e += stride) {
        int r = eidx[e], c = eidx[E + e];
        int p = atomicAdd(&offs[r], 1);
        sorted[p] = make_int2(r, c);
    }
}

// ---------------- prep: weights -> fragment-ordered bf16 ----------------
__global__ __launch_bounds__(256) void egnn_prep(
    const float* __restrict__ We1, const float* __restrict__ We2,
    const float* __restrict__ Wc1, const float* __restrict__ Wn1,
    const float* __restrict__ Wn2, u16* __restrict__ ws)
{
    int i = blockIdx.x * blockDim.x + threadIdx.x;   // 32768 threads
    u16* We1F = ws + FRAG_WE1;
    u16* We2F = ws + FRAG_WE2;
    u16* Wc1F = ws + FRAG_WC1;
    u16* Wn1F = ws + FRAG_WN1;
    u16* Wn2F = ws + FRAG_WN2;
    float* We1r = (float*)(ws + WE1R_OFF);

    if (i < 32768) {
        int j = i & 7, l = (i >> 3) & 63, kk = (i >> 9) & 7, nt = i >> 12;
        int k = kk * 32 + (l >> 4) * 8 + j;
        int n = nt * 16 + (l & 15);
        We1F[i] = f2bf(We1[k * D + n]);
        Wn1F[i] = f2bf(Wn1[k * D + n]);
    }
    if (i < 16384) {
        int j = i & 7, l = (i >> 3) & 63, kk = (i >> 9) & 3, nt = i >> 11;
        int k = kk * 32 + (l >> 4) * 8 + j;
        int n = nt * 16 + (l & 15);
        We2F[i] = f2bf(We2[k * D + n]);
        Wc1F[i] = f2bf(Wc1[k * D + n]);
        Wn2F[i] = f2bf(Wn2[k * D + n]);
    }
    if (i < 128) We1r[i] = We1[256 * D + i];
}

// ---------------- sorted edge kernel ----------------
// 64 sorted edges/block (rows ascending -> runs of equal row). Wave w owns
// cols [32w,32w+32). LDS overlay as in R5. Tail = segmented reduction:
// one pk atomic per (row-run x col-pair) instead of per edge.
__global__ __launch_bounds__(256, 4) void egnn_edge_sorted(
    const float* __restrict__ h, const float* __restrict__ pos,
    const int2* __restrict__ sorted,
    const u16* __restrict__ We1F, const float* __restrict__ We1r,
    const float* __restrict__ be1,
    const u16* __restrict__ We2F, const float* __restrict__ be2,
    const u16* __restrict__ Wc1F, const float* __restrict__ bc1,
    const float* __restrict__ Wc2,
    u16* __restrict__ aggb, float* __restrict__ pos_out, int E)
{
    __shared__ u16 A[64][264];
    __shared__ int erow[64], ecol[64];
    __shared__ float ediff[64][3], edist[64], sfac[64];

    const int tid = threadIdx.x;
    const int w = tid >> 6, l = tid & 63;
    const int q = l >> 4, m = l & 15;
    const int e0 = blockIdx.x * 64;

    if (tid < 64) {
        int e = e0 + tid;
        int r = 0, c = 0;
        if (e < E) { int2 rc = sorted[e]; r = rc.x; c = rc.y; }
        erow[tid] = r; ecol[tid] = c;
        float dx = pos[r*3+0] - pos[c*3+0];
        float dy = pos[r*3+1] - pos[c*3+1];
        float dz = pos[r*3+2] - pos[c*3+2];
        float dd = fmaxf(sqrtf(dx*dx + dy*dy + dz*dz), 1e-6f);
        ediff[tid][0] = dx; ediff[tid][1] = dy; ediff[tid][2] = dz;
        edist[tid] = dd;
    }
    __syncthreads();

    // hoist layer-1 B-frags (L2 latency overlaps the gather)
    bf16x8 B1[2][8];
    #pragma unroll
    for (int t2 = 0; t2 < 2; ++t2)
        #pragma unroll
        for (int kk = 0; kk < 8; ++kk)
            B1[t2][kk] = *(const bf16x8*)&We1F[(((2*w + t2)*8 + kk)*64 + l)*8];
    float b1_[2], wr1[2];
    #pragma unroll
    for (int t2 = 0; t2 < 2; ++t2) {
        int n = (2*w + t2)*16 + m;
        b1_[t2] = be1[n]; wr1[t2] = We1r[n];
    }

    // gather h[row] | h[col] -> bf16 LDS (sorted rows -> L1/L2 hits)
    #pragma unroll
    for (int p = 0; p < 16; ++p) {
        int el = p * 4 + w;
        int node = (l < 32) ? erow[el] : ecol[el];
        int f0 = (l & 31) * 4;
        float4 v = *(const float4*)(h + (size_t)node * D + f0);
        uint2 pk; pk.x = pk2bf(v.x, v.y); pk.y = pk2bf(v.z, v.w);
        *(uint2*)&A[el][(l >> 5) * 128 + f0] = pk;
    }
    __syncthreads();

    // ---- layer 1: t1 = silu([hR|hC|dist] @ We1 + be1), hold in regs ----
    unsigned hold[4][2][2];
    #pragma unroll
    for (int mt = 0; mt < 4; ++mt) {
        bf16x8 a[8];
        #pragma unroll
        for (int kk = 0; kk < 8; ++kk)
            a[kk] = *(const bf16x8*)&A[mt*16 + m][kk*32 + q*8];
        float ed[4];
        #pragma unroll
        for (int rg = 0; rg < 4; ++rg) ed[rg] = edist[mt*16 + q*4 + rg];
        #pragma unroll
        for (int t2 = 0; t2 < 2; ++t2) {
            f32x4 c;
            #pragma unroll
            for (int rg = 0; rg < 4; ++rg) c[rg] = fmaf(ed[rg], wr1[t2], b1_[t2]);
            #pragma unroll
            for (int kk = 0; kk < 8; ++kk)
                c = __builtin_amdgcn_mfma_f32_16x16x32_bf16(a[kk], B1[t2][kk], c, 0, 0, 0);
            hold[mt][t2][0] = pk2bf(silu_f(c[0]), silu_f(c[1]));
            hold[mt][t2][1] = pk2bf(silu_f(c[2]), silu_f(c[3]));
        }
    }
    __syncthreads();   // h_col reads done before T overlay writes

    #pragma unroll
    for (int mt = 0; mt < 4; ++mt)
        #pragma unroll
        for (int t2 = 0; t2 < 2; ++t2) {
            int n = 128 + (2*w + t2)*16 + m;
            int rb = mt*16 + q*4;
            unsigned h0 = hold[mt][t2][0], h1 = hold[mt][t2][1];
            A[rb + 0][n] = (u16)h0;
            A[rb + 1][n] = (u16)(h0 >> 16);
            A[rb + 2][n] = (u16)h1;
            A[rb + 3][n] = (u16)(h1 >> 16);
        }
    __syncthreads();

    // ---- layer 2: msg = silu(t1 @ We2 + be2); T(cols 128+) -> msg(cols 0..127) ----
    {
        bf16x8 Bf[2][4];
        #pragma unroll
        for (int t2 = 0; t2 < 2; ++t2)
            #pragma unroll
            for (int kk = 0; kk < 4; ++kk)
                Bf[t2][kk] = *(const bf16x8*)&We2F[(((2*w + t2)*4 + kk)*64 + l)*8];
        float b0[2];
        #pragma unroll
        for (int t2 = 0; t2 < 2; ++t2) b0[t2] = be2[(2*w + t2)*16 + m];
        #pragma unroll
        for (int mt = 0; mt < 4; ++mt) {
            bf16x8 a[4];
            #pragma unroll
            for (int kk = 0; kk < 4; ++kk)
                a[kk] = *(const bf16x8*)&A[mt*16 + m][128 + kk*32 + q*8];
            #pragma unroll
            for (int t2 = 0; t2 < 2; ++t2) {
                f32x4 c = { b0[t2], b0[t2], b0[t2], b0[t2] };
                #pragma unroll
                for (int kk = 0; kk < 4; ++kk)
                    c = __builtin_amdgcn_mfma_f32_16x16x32_bf16(a[kk], Bf[t2][kk], c, 0, 0, 0);
                int n = (2*w + t2)*16 + m;
                int rb = mt*16 + q*4;
                unsigned p0 = pk2bf(silu_f(c[0]), silu_f(c[1]));
                unsigned p1 = pk2bf(silu_f(c[2]), silu_f(c[3]));
                A[rb + 0][n] = (u16)p0;
                A[rb + 1][n] = (u16)(p0 >> 16);
                A[rb + 2][n] = (u16)p1;
                A[rb + 3][n] = (u16)(p1 >> 16);
            }
        }
    }
    __syncthreads();

    // ---- coord layer 1: t2 = silu(msg @ Wc1 + bc1) -> T(cols 128+) ----
    {
        bf16x8 Bf[2][4];
        #pragma unroll
        for (int t2 = 0; t2 < 2; ++t2)
            #pragma unroll
            for (int kk = 0; kk < 4; ++kk)
                Bf[t2][kk] = *(const bf16x8*)&Wc1F[(((2*w + t2)*4 + kk)*64 + l)*8];
        float b0[2];
        #pragma unroll
        for (int t2 = 0; t2 < 2; ++t2) b0[t2] = bc1[(2*w + t2)*16 + m];
        #pragma unroll
        for (int mt = 0; mt < 4; ++mt) {
            bf16x8 a[4];
            #pragma unroll
            for (int kk = 0; kk < 4; ++kk)
                a[kk] = *(const bf16x8*)&A[mt*16 + m][kk*32 + q*8];
            #pragma unroll
            for (int t2 = 0; t2 < 2; ++t2) {
                f32x4 c = { b0[t2], b0[t2], b0[t2], b0[t2] };
                #pragma unroll
                for (int kk = 0; kk < 4; ++kk)
                    c = __builtin_amdgcn_mfma_f32_16x16x32_bf16(a[kk], Bf[t2][kk], c, 0, 0, 0);
                int n = 128 + (2*w + t2)*16 + m;
                int rb = mt*16 + q*4;
                unsigned p0 = pk2bf(silu_f(c[0]), silu_f(c[1]));
                unsigned p1 = pk2bf(silu_f(c[2]), silu_f(c[3]));
                A[rb + 0][n] = (u16)p0;
                A[rb + 1][n] = (u16)(p0 >> 16);
                A[rb + 2][n] = (u16)p1;
                A[rb + 3][n] = (u16)(p1 >> 16);
            }
        }
    }
    __syncthreads();

    // ---- coord layer 2: s_e = clip(t2 . Wc2) / dist -> sfac (intra-wave) ----
    {
        int e = tid >> 2;          // edge e's 4 lanes live in wave e>>4
        int l4 = tid & 3;
        float p = 0.f;
        #pragma unroll
        for (int i = 0; i < 8; ++i) {
            int k = l4 * 32 + i * 4;
            u16x4 tv = *(const u16x4*)&A[e][128 + k];
            float4 wv = *(const float4*)&Wc2[k];
            p += bf2f(tv.x)*wv.x + bf2f(tv.y)*wv.y + bf2f(tv.z)*wv.z + bf2f(tv.w)*wv.w;
        }
        p += __shfl_xor(p, 1);
        p += __shfl_xor(p, 2);
        if (l4 == 0) {
            float cw = fminf(1.0f, fmaxf(-1.0f, p));
            sfac[e] = cw / edist[e];
        }
    }

    // ---- pos: segmented reduction over sorted rows (3 lanes/wave, 16 edges) ----
    if (l < 3) {
        float acc = 0.f; int prow = -1;
        for (int e2 = 0; e2 < 16; ++e2) {
            int e = w * 16 + e2;
            if (e0 + e >= E) break;
            int r = erow[e];
            if (r != prow) {
                if (prow >= 0) atomicAdd(&pos_out[prow*3 + l], acc);
                acc = 0.f; prow = r;
            }
            acc += ediff[e][l] * sfac[e];
        }
        if (prow >= 0) atomicAdd(&pos_out[prow*3 + l], acc);
    }

    // ---- agg: segmented reduction, one pk atomic per (row-run x col-pair) ----
    {
        int c2 = (tid & 63) * 2;        // column pair
        int seg0 = (tid >> 6) * 16;     // 16 edges per segment
        float a0 = 0.f, a1 = 0.f;
        int prow = -1;
        for (int e2 = 0; e2 < 16; ++e2) {
            int e = seg0 + e2;
            if (e0 + e >= E) break;
            int r = erow[e];
            if (r != prow) {
                if (prow >= 0)
                    pk_agg_add(&aggb[(size_t)prow * D + c2], pk2bf(a0, a1));
                a0 = 0.f; a1 = 0.f; prow = r;
            }
            unsigned pk = *(const unsigned*)&A[e][c2];
            a0 += bf2f((u16)pk);
            a1 += bf2f((u16)(pk >> 16));
        }
        if (prow >= 0)
            pk_agg_add(&aggb[(size_t)prow * D + c2], pk2bf(a0, a1));
    }
}

// ---------------- unsorted edge kernel (fallback, = R5) ----------------
template<int BA>
__global__ __launch_bounds__(256, 4) void egnn_edge_mfma(
    const float* __restrict__ h, const float* __restrict__ pos,
    const int* __restrict__ eidx,
    const u16* __restrict__ We1F, const float* __restrict__ We1r,
    const float* __restrict__ be1,
    const u16* __restrict__ We2F, const float* __restrict__ be2,
    const u16* __restrict__ Wc1F, const float* __restrict__ bc1,
    const float* __restrict__ Wc2,
    u16* __restrict__ aggb, float* __restrict__ aggf,
    float* __restrict__ pos_out, int E)
{
    __shared__ u16 A[64][264];
    __shared__ int erow[64], ecol[64];
    __shared__ float ediff[64][3], edist[64];

    const int tid = threadIdx.x;
    const int w = tid >> 6, l = tid & 63;
    const int q = l >> 4, m = l & 15;
    const int e0 = blockIdx.x * 64;

    if (tid < 64) {
        int e = e0 + tid;
        int r = 0, c = 0;
        if (e < E) { r = eidx[e]; c = eidx[E + e]; }
        erow[tid] = r; ecol[tid] = c;
        float dx = pos[r*3+0] - pos[c*3+0];
        float dy = pos[r*3+1] - pos[c*3+1];
        float dz = pos[r*3+2] - pos[c*3+2];
        float dd = fmaxf(sqrtf(dx*dx + dy*dy + dz*dz), 1e-6f);
        ediff[tid][0] = dx; ediff[tid][1] = dy; ediff[tid][2] = dz;
        edist[tid] = dd;
    }
    __syncthreads();

    bf16x8 B1[2][8];
    #pragma unroll
    for (int t2 = 0; t2 < 2; ++t2)
        #pragma unroll
        for (int kk = 0; kk < 8; ++kk)
            B1[t2][kk] = *(const bf16x8*)&We1F[(((2*w + t2)*8 + kk)*64 + l)*8];
    float b1_[2], wr1[2];
    #pragma unroll
    for (int t2 = 0; t2 < 2; ++t2) {
        int n = (2*w + t2)*16 + m;
        b1_[t2] = be1[n]; wr1[t2] = We1r[n];
    }

    #pragma unroll
    for (int p = 0; p < 16; ++p) {
        int el = p * 4 + w;
        int node = (l < 32) ? erow[el] : ecol[el];
        int f0 = (l & 31) * 4;
        float4 v = *(const float4*)(h + (size_t)node * D + f0);
        uint2 pk; pk.x = pk2bf(v.x, v.y); pk.y = pk2bf(v.z, v.w);
        *(uint2*)&A[el][(l >> 5) * 128 + f0] = pk;
    }
    __syncthreads();

    unsigned hold[4][2][2];
    #pragma unroll
    for (int mt = 0; mt < 4; ++mt) {
        bf16x8 a[8];
        #pragma unroll
        for (int kk = 0; kk < 8; ++kk)
            a[kk] = *(const bf16x8*)&A[mt*16 + m][kk*32 + q*8];
        float ed[4];
        #pragma unroll
        for (int rg = 0; rg < 4; ++rg) ed[rg] = edist[mt*16 + q*4 + rg];
        #pragma unroll
        for (int t2 = 0; t2 < 2; ++t2) {
            f32x4 c;
            #pragma unroll
            for (int rg = 0; rg < 4; ++rg) c[rg] = fmaf(ed[rg], wr1[t2], b1_[t2]);
            #pragma unroll
            for (int kk = 0; kk < 8; ++kk)
                c = __builtin_amdgcn_mfma_f32_16x16x32_bf16(a[kk], B1[t2][kk], c, 0, 0, 0);
            hold[mt][t2][0] = pk2bf(silu_f(c[0]), silu_f(c[1]));
            hold[mt][t2][1] = pk2bf(silu_f(c[2]), silu_f(c[3]));
        }
    }
    __syncthreads();

    #pragma unroll
    for (int mt = 0; mt < 4; ++mt)
        #pragma unroll
        for (int t2 = 0; t2 < 2; ++t2) {
            int n = 128 + (2*w + t2)*16 + m;
            int rb = mt*16 + q*4;
            unsigned h0 = hold[mt][t2][0], h1 = hold[mt][t2][1];
            A[rb + 0][n] = (u16)h0;
            A[rb + 1][n] = (u16)(h0 >> 16);
            A[rb + 2][n] = (u16)h1;
            A[rb + 3][n] = (u16)(h1 >> 16);
        }
    __syncthreads();

    {
        bf16x8 Bf[2][4];
        #pragma unroll
        for (int t2 = 0; t2 < 2; ++t2)
            #pragma unroll
            for (int kk = 0; kk < 4; ++kk)
                Bf[t2][kk] = *(const bf16x8*)&We2F[(((2*w + t2)*4 + kk)*64 + l)*8];
        float b0[2];
        #pragma unroll
        for (int t2 = 0; t2 < 2; ++t2) b0[t2] = be2[(2*w + t2)*16 + m];
        #pragma unroll
        for (int mt = 0; mt < 4; ++mt) {
            bf16x8 a[4];
            #pragma unroll
            for (int kk = 0; kk < 4; ++kk)
                a[kk] = *(const bf16x8*)&A[mt*16 + m][128 + kk*32 + q*8];
            #pragma unroll
            for (int t2 = 0; t2 < 2; ++t2) {
                f32x4 c = { b0[t2], b0[t2], b0[t2], b0[t2] };
                #pragma unroll
                for (int kk = 0; kk < 4; ++kk)
                    c = __builtin_amdgcn_mfma_f32_16x16x32_bf16(a[kk], Bf[t2][kk], c, 0, 0, 0);
                int n = (2*w + t2)*16 + m;
                int rb = mt*16 + q*4;
                unsigned p0 = pk2bf(silu_f(c[0]), silu_f(c[1]));
                unsigned p1 = pk2bf(silu_f(c[2]), silu_f(c[3]));
                A[rb + 0][n] = (u16)p0;
                A[rb + 1][n] = (u16)(p0 >> 16);
                A[rb + 2][n] = (u16)p1;
                A[rb + 3][n] = (u16)(p1 >> 16);
            }
        }
    }
    __syncthreads();

    {
        bf16x8 Bf[2][4];
        #pragma unroll
        for (int t2 = 0; t2 < 2; ++t2)
            #pragma unroll
            for (int kk = 0; kk < 4; ++kk)
                Bf[t2][kk] = *(const bf16x8*)&Wc1F[(((2*w + t2)*4 + kk)*64 + l)*8];
        float b0[2];
        #pragma unroll
        for (int t2 = 0; t2 < 2; ++t2) b0[t2] = bc1[(2*w + t2)*16 + m];
        #pragma unroll
        for (int mt = 0; mt < 4; ++mt) {
            bf16x8 a[4];
            #pragma unroll
            for (int kk = 0; kk < 4; ++kk)
                a[kk] = *(const bf16x8*)&A[mt*16 + m][kk*32 + q*8];
            #pragma unroll
            for (int t2 = 0; t2 < 2; ++t2) {
                f32x4 c = { b0[t2], b0[t2], b0[t2], b0[t2] };
                #pragma unroll
                for (int kk = 0; kk < 4; ++kk)
                    c = __builtin_amdgcn_mfma_f32_16x16x32_bf16(a[kk], Bf[t2][kk], c, 0, 0, 0);
                int n = 128 + (2*w + t2)*16 + m;
                int rb = mt*16 + q*4;
                unsigned p0 = pk2bf(silu_f(c[0]), silu_f(c[1]));
                unsigned p1 = pk2bf(silu_f(c[2]), silu_f(c[3]));
                A[rb + 0][n] = (u16)p0;
                A[rb + 1][n] = (u16)(p0 >> 16);
                A[rb + 2][n] = (u16)p1;
                A[rb + 3][n] = (u16)(p1 >> 16);
            }
        }
    }
    __syncthreads();

    {
        int e = tid >> 2;
        int l4 = tid & 3;
        float p = 0.f;
        #pragma unroll
        for (int i = 0; i < 8; ++i) {
            int k = l4 * 32 + i * 4;
            u16x4 tv = *(const u16x4*)&A[e][128 + k];
            float4 wv = *(const float4*)&Wc2[k];
            p += bf2f(tv.x)*wv.x + bf2f(tv.y)*wv.y + bf2f(tv.z)*wv.z + bf2f(tv.w)*wv.w;
        }
        p += __shfl_xor(p, 1);
        p += __shfl_xor(p, 2);
        if (l4 == 0 && (e0 + e) < E) {
            float cw = fminf(1.0f, fmaxf(-1.0f, p));
            float s = cw / edist[e];
            int r = erow[e];
            atomicAdd(&pos_out[r*3+0], ediff[e][0] * s);
            atomicAdd(&pos_out[r*3+1], ediff[e][1] * s);
            atomicAdd(&pos_out[r*3+2], ediff[e][2] * s);
        }
    }

    if (BA) {
        #pragma unroll
        for (int e2 = 0; e2 < 16; ++e2) {
            int e = w * 16 + e2;
            if ((e0 + e) < E) {
                int r = erow[e];
                unsigned pk = *(const unsigned*)&A[e][l * 2];
                pk_agg_add(&aggb[(size_t)r * D + l * 2], pk);
            }
        }
    } else {
        #pragma unroll
        for (int e2 = 0; e2 < 16; ++e2) {
            int e = w * 16 + e2;
            if ((e0 + e) < E) {
                int r = erow[e];
                atomicAdd(&aggf[(size_t)r * D + l],      bf2f(A[e][l]));
                atomicAdd(&aggf[(size_t)r * D + l + 64], bf2f(A[e][l + 64]));
            }
        }
    }
}

// ---------------- node kernel: h_out = h + MLP([h|agg]) ----------------
template<int BA>
__global__ __launch_bounds__(256, 4) void egnn_node_mfma(
    const float* __restrict__ h,
    const u16* __restrict__ aggb, const float* __restrict__ aggf,
    const u16* __restrict__ Wn1F, const float* __restrict__ bn1,
    const u16* __restrict__ Wn2F, const float* __restrict__ bn2,
    float* __restrict__ out, int N)
{
    __shared__ u16 A[64][264];

    const int tid = threadIdx.x;
    const int w = tid >> 6, l = tid & 63;
    const int q = l >> 4, m = l & 15;
    const int n0 = blockIdx.x * 64;

    bf16x8 B1[2][8];
    #pragma unroll
    for (int t2 = 0; t2 < 2; ++t2)
        #pragma unroll
        for (int kk = 0; kk < 8; ++kk)
            B1[t2][kk] = *(const bf16x8*)&Wn1F[(((2*w + t2)*8 + kk)*64 + l)*8];

    #pragma unroll
    for (int p = 0; p < 16; ++p) {
        int nl = p * 4 + w;
        int node = n0 + nl; if (node >= N) node = N - 1;
        int f0 = (l & 31) * 4;
        if (l < 32) {
            float4 v = *(const float4*)(h + (size_t)node * D + f0);
            uint2 pk; pk.x = pk2bf(v.x, v.y); pk.y = pk2bf(v.z, v.w);
            *(uint2*)&A[nl][f0] = pk;
        } else if (BA) {
            u16x4 v = *(const u16x4*)&aggb[(size_t)node * D + f0];
            *(u16x4*)&A[nl][128 + f0] = v;
        } else {
            float4 v = *(const float4*)(aggf + (size_t)node * D + f0);
            uint2 pk; pk.x = pk2bf(v.x, v.y); pk.y = pk2bf(v.z, v.w);
            *(uint2*)&A[nl][128 + f0] = pk;
        }
    }
    __syncthreads();

    unsigned hold[4][2][2];
    {
        float b0[2];
        #pragma unroll
        for (int t2 = 0; t2 < 2; ++t2) b0[t2] = bn1[(2*w + t2)*16 + m];
        #pragma unroll
        for (int mt = 0; mt < 4; ++mt) {
            bf16x8 a[8];
            #pragma unroll
            for (int kk = 0; kk < 8; ++kk)
                a[kk] = *(const bf16x8*)&A[mt*16 + m][kk*32 + q*8];
            #pragma unroll
            for (int t2 = 0; t2 < 2; ++t2) {
                f32x4 c = { b0[t2], b0[t2], b0[t2], b0[t2] };
                #pragma unroll
                for (int kk = 0; kk < 8; ++kk)
                    c = __builtin_amdgcn_mfma_f32_16x16x32_bf16(a[kk], B1[t2][kk], c, 0, 0, 0);
                hold[mt][t2][0] = pk2bf(silu_f(c[0]), silu_f(c[1]));
                hold[mt][t2][1] = pk2bf(silu_f(c[2]), silu_f(c[3]));
            }
        }
    }
    __syncthreads();

    #pragma unroll
    for (int mt = 0; mt < 4; ++mt)
        #pragma unroll
        for (int t2 = 0; t2 < 2; ++t2) {
            int n = 128 + (2*w + t2)*16 + m;
            int rb = mt*16 + q*4;
            unsigned h0 = hold[mt][t2][0], h1 = hold[mt][t2][1];
            A[rb + 0][n] = (u16)h0;
            A[rb + 1][n] = (u16)(h0 >> 16);
            A[rb + 2][n] = (u16)h1;
            A[rb + 3][n] = (u16)(h1 >> 16);
        }
    __syncthreads();

    {
        bf16x8 Bf[2][4];
        #pragma unroll
        for (int t2 = 0; t2 < 2; ++t2)
            #pragma unroll
            for (int kk = 0; kk < 4; ++kk)
                Bf[t2][kk] = *(const bf16x8*)&Wn2F[(((2*w + t2)*4 + kk)*64 + l)*8];
        float b0[2];
        #pragma unroll
        for (int t2 = 0; t2 < 2; ++t2) b0[t2] = bn2[(2*w + t2)*16 + m];
        #pragma unroll
        for (int mt = 0; mt < 4; ++mt) {
            bf16x8 a[4];
            #pragma unroll
            for (int kk = 0; kk < 4; ++kk)
                a[kk] = *(const bf16x8*)&A[mt*16 + m][128 + kk*32 + q*8];
            #pragma unroll
            for (int t2 = 0; t2 < 2; ++t2) {
                f32x4 c = { b0[t2], b0[t2], b0[t2], b0[t2] };
                #pragma unroll
                for (int kk = 0; kk < 4; ++kk)
                    c = __builtin_amdgcn_mfma_f32_16x16x32_bf16(a[kk], Bf[t2][kk], c, 0, 0, 0);
                int n = (2*w + t2)*16 + m;
                #pragma unroll
                for (int rg = 0; rg < 4; ++rg) {
                    int node = n0 + mt*16 + q*4 + rg;
                    if (node < N)
                        out[(size_t)node * D + n] =
                            bf2f(A[mt*16 + q*4 + rg][n]) + c[rg];
                }
            }
        }
    }
}

extern "C" void kernel_launch(void* const* d_in, const int* in_sizes, int n_in,
                              void* d_out, int out_size, void* d_ws, size_t ws_size,
                              hipStream_t stream)
{
    const float* h   = (const float*)d_in[0];
    const float* pos = (const float*)d_in[1];
    const int*   eidx= (const int*)d_in[2];
    const float* We1 = (const float*)d_in[3];
    const float* be1 = (const float*)d_in[4];
    const float* We2 = (const float*)d_in[5];
    const float* be2 = (const float*)d_in[6];
    const float* Wn1 = (const float*)d_in[7];
    const float* bn1 = (const float*)d_in[8];
    const float* Wn2 = (const float*)d_in[9];
    const float* bn2 = (const float*)d_in[10];
    const float* Wc1 = (const float*)d_in[11];
    const float* bc1 = (const float*)d_in[12];
    const float* Wc2 = (const float*)d_in[13];

    const int N = in_sizes[0] / D;
    const int E = in_sizes[2] / 2;

    float* out     = (float*)d_out;
    float* pos_out = out + (size_t)N * D;

    char* wsb = (char*)d_ws;
    u16* ws = (u16*)d_ws;
    const u16* We1F = ws + FRAG_WE1;
    const u16* We2F = ws + FRAG_WE2;
    const u16* Wc1F = ws + FRAG_WC1;
    const u16* Wn1F = ws + FRAG_WN1;
    const u16* Wn2F = ws + FRAG_WN2;
    const float* We1r = (const float*)(ws + WE1R_OFF);

    const size_t aggOff  = FRAG_BYTES;                       // bf16 agg[N*D]
    const size_t cntOff  = aggOff + (size_t)N * D * 2;       // int[N]
    const size_t offsOff = cntOff + (size_t)N * 4;           // int[N]
    const size_t sortOff = offsOff + (size_t)N * 4;          // int2[E]
    const size_t needSorted = sortOff + (size_t)E * 8;
    const size_t needBa     = cntOff;

    u16*   aggb   = (u16*)(wsb + aggOff);
    int*   count  = (int*)(wsb + cntOff);
    int*   offs   = (int*)(wsb + offsOff);
    int2*  sorted = (int2*)(wsb + sortOff);
    float* aggf   = out;

    egnn_prep<<<128, 256, 0, stream>>>(We1, We2, Wc1, Wn1, Wn2, ws);

    if (ws_size >= needSorted) {
        egnn_zero<<<2048, 256, 0, stream>>>(pos, out, (uint4*)aggb, count, N);
        egnn_count<<<1024, 256, 0, stream>>>(eidx, count, E);
        egnn_scan<<<1, 256, 0, stream>>>(count, offs, N);
        egnn_scatter<<<1024, 256, 0, stream>>>(eidx, offs, sorted, E);
        egnn_edge_sorted<<<(E + 63) / 64, 256, 0, stream>>>(
            h, pos, sorted, We1F, We1r, be1, We2F, be2, Wc1F, bc1, Wc2,
            aggb, pos_out, E);
        egnn_node_mfma<1><<<(N + 63) / 64, 256, 0, stream>>>(
            h, aggb, aggf, Wn1F, bn1, Wn2F, bn2, out, N);
    } else if (ws_size >= needBa) {
        egnn_zero<<<2048, 256, 0, stream>>>(pos, out, (uint4*)aggb,
                                            (int*)(wsb + aggOff), 0 /*no count*/);
        egnn_init_f32<<<1, 1, 0, stream>>>(pos, out, 0);   // no-op filler
        egnn_edge_mfma<1><<<(E + 63) / 64, 256, 0, stream>>>(
            h, pos, eidx, We1F, We1r, be1, We2F, be2, Wc1F, bc1, Wc2,
            aggb, aggf, pos_out, E);
        egnn_node_mfma<1><<<(N + 63) / 64, 256, 0, stream>>>(
            h, aggb, aggf, Wn1F, bn1, Wn2F, bn2, out, N);
    } else {
        egnn_init_f32<<<2048, 256, 0, stream>>>(pos, out, N);
        egnn_edge_mfma<0><<<(E + 63) / 64, 256, 0, stream>>>(
            h, pos, eidx, We1F, We1r, be1, We2F, be2, Wc1F, bc1, Wc2,
            aggb, aggf, pos_out, E);
        egnn_node_mfma<0><<<(N + 63) / 64, 256, 0, stream>>>(
            h, aggb, aggf, Wn1F, bn1, Wn2F, bn2, out, N);
    }
}